// Round 1
// baseline (75502.997 us; speedup 1.0000x reference)
//
#include <hip/hip_runtime.h>
#include <hip/hip_bf16.h>

typedef unsigned int u32;
typedef unsigned short u16;
using half2_t = __attribute__((ext_vector_type(2))) _Float16;
using half8   = __attribute__((ext_vector_type(8))) _Float16;
using f32x4   = __attribute__((ext_vector_type(4))) float;

// Problem dims
#define TT 16384
#define HDIM 2048
#define N3H 6144
#define ODIM 1000

// Workspace layout (bytes). Total = 318,785,536 (~304 MB)
#define WS_WPACK 0ull                 // 25,165,824  : W_hh packed f16 pairs
#define WS_XH    25165824ull          // 67,108,864  : x as f16
#define WS_WIHH  92274688ull          // 25,165,824  : W_ih as f16
#define WS_IG    117440512ull         // 201,326,592 : igates f16 [T][6144]
#define WS_HBUF  318767104ull         // 16,384      : h double buffer fp32 [2][2048]
#define WS_CNT   318783488ull         // 2,048       : 16 counters, stride 32 dwords
#define WS_NEED  318785536ull

#if __has_builtin(__builtin_amdgcn_fdot2)
__device__ __forceinline__ float fdot2u(u32 a, u32 b, float c) {
  return __builtin_amdgcn_fdot2(__builtin_bit_cast(half2_t, a),
                                __builtin_bit_cast(half2_t, b), c, false);
}
#else
__device__ __forceinline__ float fdot2u(u32 a, u32 b, float c) {
  half2_t x = __builtin_bit_cast(half2_t, a), y = __builtin_bit_cast(half2_t, b);
  return c + (float)x[0] * (float)y[0] + (float)x[1] * (float)y[1];
}
#endif

// ---------------- init: zero the 16 barrier counters (agent scope) ------------
__global__ void k_init(u32* cnt) {
  if (threadIdx.x < 16)
    __hip_atomic_store(cnt + threadIdx.x * 32, 0u, __ATOMIC_RELAXED,
                       __HIP_MEMORY_SCOPE_AGENT);
}

// ---------------- fp32 -> f16 convert, 4 elems/thread ------------------------
__global__ __launch_bounds__(256) void k_conv_f16(const float* __restrict__ in,
                                                  _Float16* __restrict__ out,
                                                  int n4) {
  int i = blockIdx.x * 256 + threadIdx.x;
  if (i >= n4) return;
  float4 v = ((const float4*)in)[i];
  u32 lo = (u32)__builtin_bit_cast(u16, (_Float16)v.x) |
           ((u32)__builtin_bit_cast(u16, (_Float16)v.y) << 16);
  u32 hi = (u32)__builtin_bit_cast(u16, (_Float16)v.z) |
           ((u32)__builtin_bit_cast(u16, (_Float16)v.w) << 16);
  ((uint2*)out)[i] = make_uint2(lo, hi);
}

// ---------------- pack W_hh into per-(hrow,wave,lane) f16-pair layout --------
// dword idx = hrow*3072 + c*256 + lane*4 + q ; dl=c*4+q ; g=dl/16 ; m=dl%16
// value = (W_hh[g*2048+hrow][2*(lane*16+m)], ...+1)
__global__ __launch_bounds__(256) void k_pack(const float* __restrict__ whh,
                                              u32* __restrict__ outp) {
  u32 idx = blockIdx.x * 256 + threadIdx.x;  // < 6,291,456
  u32 hrow = idx / 3072;
  u32 rem = idx - hrow * 3072;
  u32 c = rem >> 8;
  u32 lane = (rem >> 2) & 63;
  u32 q = rem & 3;
  u32 dl = c * 4 + q;
  u32 g = dl >> 4;
  u32 m = dl & 15;
  u32 kp = lane * 16 + m;
  const float* src = whh + (size_t)(g * 2048 + hrow) * 2048 + 2 * kp;
  half2_t p;
  p[0] = (_Float16)src[0];
  p[1] = (_Float16)src[1];
  outp[idx] = __builtin_bit_cast(u32, p);
}

// ---------------- igates GEMM: C[m][n] = sum_k x[m][k]*Wih[n][k] + bias[n] ----
// 128x128 tile, BK=32, 4 waves (2x2), mfma_f32_16x16x32_f16
__global__ __launch_bounds__(256) void k_gemm(const _Float16* __restrict__ A,
                                              const _Float16* __restrict__ B,
                                              const float* __restrict__ bias,
                                              _Float16* __restrict__ Cout) {
  __shared__ __align__(16) _Float16 As[128 * 32];
  __shared__ __align__(16) _Float16 Bs[128 * 32];
  const int tid = threadIdx.x;
  const int l = tid & 63, w = tid >> 6;
  const int wr = w >> 1, wc = w & 1;
  const int m0 = blockIdx.x * 128, n0 = blockIdx.y * 128;
  const int srow = tid >> 2;            // 0..63
  const int scol = (tid & 3) << 3;      // 0,8,16,24 (f16 elems)
  f32x4 acc[4][4] = {};

  for (int k0 = 0; k0 < HDIM; k0 += 32) {
    __syncthreads();
    uint4 a0 = *(const uint4*)(A + (size_t)(m0 + srow) * HDIM + k0 + scol);
    uint4 a1 = *(const uint4*)(A + (size_t)(m0 + 64 + srow) * HDIM + k0 + scol);
    uint4 b0 = *(const uint4*)(B + (size_t)(n0 + srow) * HDIM + k0 + scol);
    uint4 b1 = *(const uint4*)(B + (size_t)(n0 + 64 + srow) * HDIM + k0 + scol);
    *(uint4*)(As + srow * 32 + scol) = a0;
    *(uint4*)(As + (64 + srow) * 32 + scol) = a1;
    *(uint4*)(Bs + srow * 32 + scol) = b0;
    *(uint4*)(Bs + (64 + srow) * 32 + scol) = b1;
    __syncthreads();
    half8 av[4], bv[4];
#pragma unroll
    for (int mi = 0; mi < 4; ++mi)
      av[mi] = *(const half8*)(As + (wr * 64 + mi * 16 + (l & 15)) * 32 + (l >> 4) * 8);
#pragma unroll
    for (int ni = 0; ni < 4; ++ni)
      bv[ni] = *(const half8*)(Bs + (wc * 64 + ni * 16 + (l & 15)) * 32 + (l >> 4) * 8);
#pragma unroll
    for (int mi = 0; mi < 4; ++mi)
#pragma unroll
      for (int ni = 0; ni < 4; ++ni)
        acc[mi][ni] = __builtin_amdgcn_mfma_f32_16x16x32_f16(av[mi], bv[ni], acc[mi][ni], 0, 0, 0);
  }
#pragma unroll
  for (int ni = 0; ni < 4; ++ni) {
    int col = n0 + wc * 64 + ni * 16 + (l & 15);
    float bb = bias[col];
#pragma unroll
    for (int mi = 0; mi < 4; ++mi) {
      int rbase = m0 + wr * 64 + mi * 16 + (l >> 4) * 4;
#pragma unroll
      for (int r = 0; r < 4; ++r)
        Cout[(size_t)(rbase + r) * N3H + col] = (_Float16)(acc[mi][ni][r] + bb);
    }
  }
}

// ---------------- persistent GRU scan: 256 WGs x 512 thr, coop launch --------
// Wave w of WG wg owns h-row hrow = wg*8+w (its r,z,n gate rows).
// W_hh slice lives in registers (48 dwords of f16 pairs per lane).
// Lane l covers k in [32l, 32l+32). Grid barrier: 16 monotonic counters.
__global__ __launch_bounds__(512) void k_scan(const uint4* __restrict__ wpack,
                                              const _Float16* __restrict__ ig,
                                              const float* __restrict__ bias_n,
                                              float* hbuf, u32* cnt) {
  __shared__ __align__(16) u32 lds_h[1280];  // 1024 f16-pair dwords + pad 4/16
  const int tid = threadIdx.x;
  const int l = tid & 63, w = tid >> 6;
  const int wg = blockIdx.x;
  const int hrow = wg * 8 + w;

  u32 wdw[48];
  {
    const uint4* wp = wpack + (size_t)hrow * 12 * 64 + l;
#pragma unroll
    for (int c = 0; c < 12; ++c) {
      uint4 v = wp[(size_t)c * 64];
      wdw[c * 4] = v.x; wdw[c * 4 + 1] = v.y; wdw[c * 4 + 2] = v.z; wdw[c * 4 + 3] = v.w;
    }
  }
  const float bn = bias_n[hrow];
  float hm = 0.f;  // fp32 master state (valid in lane 0)
  u32 hreg[16];
#pragma unroll
  for (int m = 0; m < 16; ++m) hreg[m] = 0;  // h(0) = 0

  // prefetch igates row 0 (all lanes, same addr -> broadcast)
  float ig0 = (float)ig[hrow], ig1 = (float)ig[2048 + hrow], ig2 = (float)ig[4096 + hrow];

  for (int t = 0; t < TT; ++t) {
    float igr = ig0, igz = ig1, ign = ig2;
    float a0 = 0.f, a1 = 0.f, a2 = 0.f, b0 = 0.f, b1 = 0.f, b2 = 0.f;
#pragma unroll
    for (int m = 0; m < 16; m += 2) {
      a0 = fdot2u(wdw[m],          hreg[m],     a0);
      b0 = fdot2u(wdw[m + 1],      hreg[m + 1], b0);
      a1 = fdot2u(wdw[16 + m],     hreg[m],     a1);
      b1 = fdot2u(wdw[16 + m + 1], hreg[m + 1], b1);
      a2 = fdot2u(wdw[32 + m],     hreg[m],     a2);
      b2 = fdot2u(wdw[32 + m + 1], hreg[m + 1], b2);
    }
    float s0 = a0 + b0, s1 = a1 + b1, s2 = a2 + b2;
#pragma unroll
    for (int off = 1; off < 64; off <<= 1) {
      s0 += __shfl_xor(s0, off, 64);
      s1 += __shfl_xor(s1, off, 64);
      s2 += __shfl_xor(s2, off, 64);
    }
    float* hdst = hbuf + (((t + 1) & 1) << 11);
    if (l == 0) {
      float r = 1.f / (1.f + __expf(-(igr + s0)));
      float z = 1.f / (1.f + __expf(-(igz + s1)));
      float nx = ign + r * (s2 + bn);
      float e = __expf(-2.f * nx);
      float n = (1.f - e) / (1.f + e);
      hm = n + z * (hm - n);
      __hip_atomic_store(hdst + hrow, hm, __ATOMIC_RELAXED, __HIP_MEMORY_SCOPE_AGENT);
    }
    asm volatile("s_waitcnt vmcnt(0)" ::: "memory");  // h store at L3 before arrival
    __syncthreads();
    if (t == TT - 1) break;
    if (tid == 0)
      __hip_atomic_fetch_add(cnt + (wg & 15) * 32, 1u, __ATOMIC_RELAXED,
                             __HIP_MEMORY_SCOPE_AGENT);
    {  // prefetch next igates row (overlaps the spin)
      const _Float16* igp = ig + (size_t)(t + 1) * N3H;
      ig0 = (float)igp[hrow]; ig1 = (float)igp[2048 + hrow]; ig2 = (float)igp[4096 + hrow];
    }
    if (w == 0 && l < 16) {  // wave 0 spins on 16 counters
      const u32 tgt = 16u * (u32)(t + 1);
      const u32* cp = cnt + l * 32;
      while (__hip_atomic_load(cp, __ATOMIC_RELAXED, __HIP_MEMORY_SCOPE_AGENT) < tgt) {}
    }
    __syncthreads();
    {  // redistribute h(t+1): global(L3, agent) -> f16 pairs -> LDS
      const float* hsrc = hdst;
      unsigned long long v0 = __hip_atomic_load((const unsigned long long*)(hsrc + 4 * tid),
                                                __ATOMIC_RELAXED, __HIP_MEMORY_SCOPE_AGENT);
      unsigned long long v1 = __hip_atomic_load((const unsigned long long*)(hsrc + 4 * tid + 2),
                                                __ATOMIC_RELAXED, __HIP_MEMORY_SCOPE_AGENT);
      half2_t p0, p1;
      p0[0] = (_Float16)__uint_as_float((u32)v0);
      p0[1] = (_Float16)__uint_as_float((u32)(v0 >> 32));
      p1[0] = (_Float16)__uint_as_float((u32)v1);
      p1[1] = (_Float16)__uint_as_float((u32)(v1 >> 32));
      u32* dst = lds_h + 2 * tid + ((tid >> 3) << 2);  // pad 4 dwords per 16
      dst[0] = __builtin_bit_cast(u32, p0);
      dst[1] = __builtin_bit_cast(u32, p1);
    }
    __syncthreads();
#pragma unroll
    for (int i = 0; i < 4; ++i) {
      uint4 v = *(const uint4*)(lds_h + l * 20 + i * 4);
      hreg[i * 4] = v.x; hreg[i * 4 + 1] = v.y; hreg[i * 4 + 2] = v.z; hreg[i * 4 + 3] = v.w;
    }
  }
}

// ---------------- final projection: out = w_out @ h_final + b_out + b_extra --
__global__ __launch_bounds__(256) void k_out(const float* __restrict__ wout,
                                             const float* __restrict__ bout,
                                             const float* __restrict__ bextra,
                                             const float* __restrict__ h,
                                             float* __restrict__ out) {
  const int l = threadIdx.x & 63;
  const int o = blockIdx.x * 4 + (threadIdx.x >> 6);
  if (o >= ODIM) return;
  const float* wr = wout + (size_t)o * HDIM;
  float acc = 0.f;
#pragma unroll
  for (int i = 0; i < 8; ++i) {
    float4 wv = *(const float4*)(wr + i * 256 + l * 4);
    float4 hv = *(const float4*)(h + i * 256 + l * 4);
    acc += wv.x * hv.x + wv.y * hv.y + wv.z * hv.z + wv.w * hv.w;
  }
#pragma unroll
  for (int off = 1; off < 64; off <<= 1) acc += __shfl_xor(acc, off, 64);
  if (l == 0) out[o] = acc + bout[o] + bextra[o];
}

// sentinel if workspace too small: absmax ~= 1e6 + ws_size_in_MB (debug channel)
__global__ void k_dbg(float* out, float v) {
  int i = blockIdx.x * 256 + threadIdx.x;
  if (i < ODIM) out[i] = v;
}

extern "C" void kernel_launch(void* const* d_in, const int* in_sizes, int n_in,
                              void* d_out, int out_size, void* d_ws, size_t ws_size,
                              hipStream_t stream) {
  const float* x      = (const float*)d_in[0];
  const float* wih    = (const float*)d_in[1];
  const float* whh    = (const float*)d_in[2];
  const float* bias   = (const float*)d_in[3];
  const float* bias_n = (const float*)d_in[4];
  const float* wout   = (const float*)d_in[5];
  const float* bout   = (const float*)d_in[6];
  const float* bextra = (const float*)d_in[7];
  float* out = (float*)d_out;

  if (ws_size < WS_NEED) {
    k_dbg<<<4, 256, 0, stream>>>(out, 1.0e6f + (float)(ws_size / 1048576ull));
    return;
  }

  char* ws = (char*)d_ws;
  u32*      wpack = (u32*)(ws + WS_WPACK);
  _Float16* xh    = (_Float16*)(ws + WS_XH);
  _Float16* wihh  = (_Float16*)(ws + WS_WIHH);
  _Float16* igb   = (_Float16*)(ws + WS_IG);
  float*    hbuf  = (float*)(ws + WS_HBUF);
  u32*      cnt   = (u32*)(ws + WS_CNT);

  k_init<<<1, 64, 0, stream>>>(cnt);
  k_conv_f16<<<8388608 / 256, 256, 0, stream>>>(x, xh, 8388608);        // 16384*2048/4
  k_conv_f16<<<3145728 / 256, 256, 0, stream>>>(wih, wihh, 3145728);    // 6144*2048/4
  k_pack<<<24576, 256, 0, stream>>>(whh, wpack);                        // 6,291,456 dwords
  k_gemm<<<dim3(128, 48), 256, 0, stream>>>(xh, wihh, bias, igb);

  const uint4* wpc = (const uint4*)wpack;
  const _Float16* igc = igb;
  void* kargs[] = {(void*)&wpc, (void*)&igc, (void*)&bias_n, (void*)&hbuf, (void*)&cnt};
  hipLaunchCooperativeKernel(k_scan, dim3(256), dim3(512), kargs, 0, stream);

  k_out<<<250, 256, 0, stream>>>(wout, bout, bextra, hbuf, out);
}